// Round 8
// baseline (336.949 us; speedup 1.0000x reference)
//
#include <hip/hip_runtime.h>
#include <hip/hip_bf16.h>

#define H  1024
#define S  32768
#define H2 2048
#define H3 3072

typedef __attribute__((ext_vector_type(8))) short bf16x8;   // 8 bf16 = 4 VGPRs
typedef __attribute__((ext_vector_type(4))) float f32x4;    // MFMA C/D frag

// ---------- fp32 -> bf16 (RNE) helpers ----------
__device__ __forceinline__ unsigned short f2bf(float f) {
    unsigned u = __float_as_uint(f);
    u += 0x7fffu + ((u >> 16) & 1u);
    return (unsigned short)(u >> 16);
}

__device__ __forceinline__ unsigned cvt_pk(float lo, float hi) {
    __hip_bfloat162 h = __float22bfloat162_rn(make_float2(lo, hi));
    unsigned u;
    __builtin_memcpy(&u, &h, 4);
    return u;
}

// fast tanh via v_exp_f32: tanh(x) = 1 - 2/(e^(2x)+1)
__device__ __forceinline__ float tanh_fast(float x) {
    float e = __expf(2.0f * x);
    return 1.0f - 2.0f / (e + 1.0f);
}

// ---------- async global->LDS 16B ----------
__device__ __forceinline__ void async_copy16(const void* g, void* l) {
    __builtin_amdgcn_global_load_lds(
        (const __attribute__((address_space(1))) unsigned int*)g,
        (__attribute__((address_space(3))) unsigned int*)l,
        16, 0, 0);
}

// ---------- fused prep (PROVEN round-0/6 function, verbatim) ----------
// launched with do_enc=0: zero logits, W2->bf16, dvec only (~15 MB traffic)
__global__ void prep_all(const float* __restrict__ enc, const float* __restrict__ attn_w,
                         const float* __restrict__ attn_b, const float* __restrict__ hidden,
                         unsigned short* __restrict__ ebf, unsigned short* __restrict__ w2b,
                         float* __restrict__ dvec, float* __restrict__ logits, int do_enc) {
    int b = blockIdx.x;
    if (b < 32) {
        // zero the logits (gemm accumulates via atomicAdd)
        ((float4*)logits)[b * 256 + threadIdx.x] = (float4){0.f, 0.f, 0.f, 0.f};
        return;
    }
    b -= 32;
    if (do_enc) {
        if (b < 32768) {
            size_t idx4 = (size_t)b * 256 + threadIdx.x;       // float4 chunk id
            float4 f = ((const float4*)enc)[idx4];
            ushort4 u;
            u.x = f2bf(f.x); u.y = f2bf(f.y); u.z = f2bf(f.z); u.w = f2bf(f.w);
            ((ushort4*)ebf)[idx4] = u;
            return;
        }
        b -= 32768;
    }
    if (b < 1024) {
        // W2 = attn_w[:, 2048:3072] -> bf16 row-major (N=1024 x K=1024)
        int idx4 = b * 256 + threadIdx.x;
        int n = idx4 >> 8;
        int c = (idx4 & 255) * 4;
        float4 f = *(const float4*)(attn_w + (size_t)n * H3 + H2 + c);
        ushort4 u;
        u.x = f2bf(f.x); u.y = f2bf(f.y); u.z = f2bf(f.z); u.w = f2bf(f.w);
        *(ushort4*)(w2b + (size_t)n * H + c) = u;
        return;
    }
    // dvec[i] = attn_b[i] + sum_{k<2048} hidden[k]*attn_w[i][k]
    b -= 1024;
    int wv = threadIdx.x >> 6, lane = threadIdx.x & 63;
    int row = b * 4 + wv;
    const float* wrow = attn_w + (size_t)row * H3;
    float s = 0.f;
    #pragma unroll
    for (int j = 0; j < 32; ++j) {
        int k = lane + j * 64;
        s += wrow[k] * hidden[k];
    }
    #pragma unroll
    for (int m = 1; m <= 32; m <<= 1) s += __shfl_xor(s, m);
    if (lane == 0) dvec[row] = s + attn_b[row];
}

// ---------- shared epilogue: tanh + v_w-dot + shuffle-reduce + atomic ----------
__device__ __forceinline__ void epilogue(const f32x4 acc[4][4], const float* __restrict__ dvec,
                                         const float* __restrict__ vw, float* __restrict__ logits,
                                         int rowBlock, int colBlock, int waveM, int waveN,
                                         int quad, int l16) {
    float rowsum[4][4];
    #pragma unroll
    for (int mi = 0; mi < 4; ++mi)
        #pragma unroll
        for (int r = 0; r < 4; ++r) rowsum[mi][r] = 0.f;

    #pragma unroll
    for (int ni = 0; ni < 4; ++ni) {
        int colg = colBlock * 128 + waveN * 64 + ni * 16 + l16;
        float dv = dvec[colg];
        float vv = vw[colg];
        #pragma unroll
        for (int mi = 0; mi < 4; ++mi)
            #pragma unroll
            for (int r = 0; r < 4; ++r)
                rowsum[mi][r] += tanh_fast(acc[mi][ni][r] + dv) * vv;
    }

    #pragma unroll
    for (int mi = 0; mi < 4; ++mi)
        #pragma unroll
        for (int r = 0; r < 4; ++r) {
            float s = rowsum[mi][r];
            s += __shfl_xor(s, 1);
            s += __shfl_xor(s, 2);
            s += __shfl_xor(s, 4);
            s += __shfl_xor(s, 8);
            rowsum[mi][r] = s;
        }

    if (l16 == 0) {
        int rbase = rowBlock * 128 + waveM * 64 + quad * 4;
        #pragma unroll
        for (int mi = 0; mi < 4; ++mi)
            #pragma unroll
            for (int r = 0; r < 4; ++r)
                atomicAdd(&logits[rbase + mi * 16 + r], rowsum[mi][r]);
    }
}

// ---------- fused gemm, PURE global_load_lds staging for BOTH operands ----------
// A is staged as RAW FP32 (no pre-conversion pass, no reg-staged global loads,
// no ds_write — the two structural suspects from the crashed variants are gone).
// fp32->bf16 conversion happens on the LDS->register read path before MFMA.
//
// tile BM=128 BN=128 BK=64; 256 threads (2x2 waves, 64x64/wave); 16 k-iters.
// Grid decode: rowBlock = blockIdx&255 -> all 8 colBlocks of a row on one XCD.
//
// A LDS layout (fp32, 128 rows x 64 k = 32 KB): row = 256 B = 16 chunks of 16B;
//   slot j of row r holds k-chunk (j ^ ((r&7)<<1)).  EVEN XOR keeps each
//   fragment's 32 B (two adjacent chunks) contiguous; spreads 16 fragment rows
//   over 8 bank positions -> residual 2-way conflict = free (m136).
// B LDS layout (bf16, proven round-0): row = 128 B = 8 chunks; slot j holds
//   k-chunk (j ^ (r&7)); consumer slot = (kk*4+quad)^(l16&7); conflicts = 0.
__global__ __launch_bounds__(256, 2) void attn_gemm_f32a(
        const float* __restrict__ enc, const unsigned short* __restrict__ w2b,
        const float* __restrict__ dvec, const float* __restrict__ vw,
        float* __restrict__ logits) {
    __shared__ float Af[128 * 64];               // 32 KB fp32 A tile
    __shared__ unsigned short Btile[128 * 64];   // 16 KB bf16 B tile

    const int tid = threadIdx.x;
    const int rowBlock = blockIdx.x & 255;       // XCD-affine: row -> fixed XCD
    const int colBlock = blockIdx.x >> 8;        // 0..7

    const int lane = tid & 63;
    const int wv = tid >> 6;
    const int waveM = wv >> 1, waveN = wv & 1;
    const int quad = lane >> 4, l16 = lane & 15;

    f32x4 acc[4][4];
    #pragma unroll
    for (int mi = 0; mi < 4; ++mi)
        #pragma unroll
        for (int ni = 0; ni < 4; ++ni)
            acc[mi][ni] = (f32x4){0.f, 0.f, 0.f, 0.f};

    const size_t aRow0 = (size_t)(rowBlock * 128) * H;   // fp32 elements
    const size_t bRow0 = (size_t)(colBlock * 128) * H;   // bf16 elements

    // A staging: 2048 chunks of 16B; 8 per thread. c = chunk id.
    // row = c>>4, slot = c&15, global k-elem offset = (slot ^ ((row&7)<<1))*4
    int srA[8], skA[8];
    #pragma unroll
    for (int p = 0; p < 8; ++p) {
        int c = p * 256 + tid;
        srA[p] = c >> 4;
        skA[p] = ((c & 15) ^ ((srA[p] & 7) << 1)) * 4;
    }
    // B staging: 1024 chunks; 4 per thread. row = c>>3, slot = c&7,
    // global k-elem offset = ((slot ^ (row&7)) * 8)
    int srB[4], skB[4];
    #pragma unroll
    for (int p = 0; p < 4; ++p) {
        int c = p * 256 + tid;
        srB[p] = c >> 3;
        skB[p] = ((c & 7) ^ (srB[p] & 7)) * 8;
    }

    for (int kt = 0; kt < 16; ++kt) {
        const int k0 = kt * 64;

        // A: fp32 tile via pure global_load_lds (8 x 16B per thread)
        #pragma unroll
        for (int p = 0; p < 8; ++p) {
            int c = p * 256 + tid;
            async_copy16(enc + aRow0 + (size_t)srA[p] * H + k0 + skA[p],
                         (char*)Af + (size_t)c * 16);
        }
        // B: bf16 tile via pure global_load_lds (4 x 16B per thread)
        #pragma unroll
        for (int p = 0; p < 4; ++p) {
            int c = p * 256 + tid;
            async_copy16(w2b + bRow0 + (size_t)srB[p] * H + k0 + skB[p],
                         (char*)Btile + (size_t)c * 16);
        }

        __syncthreads();   // compiler drains vmcnt(0) before barrier

        #pragma unroll
        for (int kk = 0; kk < 2; ++kk) {
            const int bslot = ((kk * 4 + quad) ^ (l16 & 7)) * 16;  // B byte offset
            bf16x8 af[4], bfr[4];
            #pragma unroll
            for (int i = 0; i < 4; ++i) {
                int ar = waveM * 64 + i * 16 + l16;
                // fragment k-chunks {base, base+1}; stored at {base^swz, +1}
                int cbase = (kk * 8 + quad * 2) ^ ((ar & 7) << 1);
                const float* ap = Af + ar * 64 + cbase * 4;
                float4 lo = ((const float4*)ap)[0];
                float4 hi = ((const float4*)ap)[1];
                uint4 u;
                u.x = cvt_pk(lo.x, lo.y);
                u.y = cvt_pk(lo.z, lo.w);
                u.z = cvt_pk(hi.x, hi.y);
                u.w = cvt_pk(hi.z, hi.w);
                __builtin_memcpy(&af[i], &u, 16);

                int br = waveN * 64 + i * 16 + l16;
                bfr[i] = *(const bf16x8*)((const char*)Btile + br * 128 + bslot);
            }
            #pragma unroll
            for (int mi = 0; mi < 4; ++mi)
                #pragma unroll
                for (int ni = 0; ni < 4; ++ni)
                    acc[mi][ni] = __builtin_amdgcn_mfma_f32_16x16x32_bf16(
                        af[mi], bfr[ni], acc[mi][ni], 0, 0, 0);
        }

        __syncthreads();   // tile consumed; next iter may overwrite
    }

    epilogue(acc, dvec, vw, logits, rowBlock, colBlock, waveM, waveN, quad, l16);
}

// ---------- softmax over 32768 logits, single workgroup, in-place ----------
__global__ __launch_bounds__(1024) void softmax_k(float* __restrict__ x) {
    __shared__ float red[16];
    const int tid = threadIdx.x;
    const int lane = tid & 63, wv = tid >> 6;

    float v[32];
    float m = -1e30f;
    #pragma unroll
    for (int i = 0; i < 32; ++i) {
        v[i] = x[tid + (i << 10)];
        m = fmaxf(m, v[i]);
    }
    #pragma unroll
    for (int o = 1; o < 64; o <<= 1) m = fmaxf(m, __shfl_xor(m, o));
    if (lane == 0) red[wv] = m;
    __syncthreads();
    #pragma unroll
    for (int i = 0; i < 16; ++i) m = fmaxf(m, red[i]);
    __syncthreads();

    float s = 0.f;
    #pragma unroll
    for (int i = 0; i < 32; ++i) {
        v[i] = expf(v[i] - m);
        s += v[i];
    }
    #pragma unroll
    for (int o = 1; o < 64; o <<= 1) s += __shfl_xor(s, o);
    if (lane == 0) red[wv] = s;
    __syncthreads();
    float tot = 0.f;
    #pragma unroll
    for (int i = 0; i < 16; ++i) tot += red[i];
    float inv = 1.0f / tot;

    #pragma unroll
    for (int i = 0; i < 32; ++i) x[tid + (i << 10)] = v[i] * inv;
}

extern "C" void kernel_launch(void* const* d_in, const int* in_sizes, int n_in,
                              void* d_out, int out_size, void* d_ws, size_t ws_size,
                              hipStream_t stream) {
    const float* hidden = (const float*)d_in[0];   // (1, 2048)
    const float* enc    = (const float*)d_in[1];   // (32768, 1024)
    const float* attn_w = (const float*)d_in[2];   // (1024, 3072)
    const float* attn_b = (const float*)d_in[3];   // (1024,)
    const float* v_w    = (const float*)d_in[4];   // (1, 1024)
    float* out = (float*)d_out;                    // (32768,) fp32

    const size_t W2_BYTES = (size_t)H * H * 2;     // 2 MB
    unsigned short* w2b = (unsigned short*)d_ws;
    float* dvec = (float*)((char*)d_ws + W2_BYTES);

    // prep (proven function, do_enc=0): zero logits + W2->bf16 + dvec
    prep_all<<<dim3(32 + 1024 + 256), dim3(256), 0, stream>>>(
        enc, attn_w, attn_b, hidden, nullptr, w2b, dvec, out, 0);
    attn_gemm_f32a<<<dim3(2048), dim3(256), 0, stream>>>(enc, w2b, dvec, v_w, out);
    softmax_k<<<dim3(1), dim3(1024), 0, stream>>>(out);
}

// Round 9
// 323.685 us; speedup vs baseline: 1.0410x; 1.0410x over previous
//
#include <hip/hip_runtime.h>
#include <hip/hip_bf16.h>

#define H  1024
#define S  32768
#define H2 2048
#define H3 3072

typedef __attribute__((ext_vector_type(8))) short bf16x8;   // 8 bf16 = 4 VGPRs
typedef __attribute__((ext_vector_type(4))) float f32x4;    // MFMA C/D frag

// ---------- fp32 -> bf16 (RNE) helpers ----------
__device__ __forceinline__ unsigned short f2bf(float f) {
    unsigned u = __float_as_uint(f);
    u += 0x7fffu + ((u >> 16) & 1u);
    return (unsigned short)(u >> 16);
}

__device__ __forceinline__ unsigned cvt_pk(float lo, float hi) {
    __hip_bfloat162 h = __float22bfloat162_rn(make_float2(lo, hi));
    unsigned u;
    __builtin_memcpy(&u, &h, 4);
    return u;
}

// fast tanh via v_exp_f32: tanh(x) = 1 - 2/(e^(2x)+1)
__device__ __forceinline__ float tanh_fast(float x) {
    float e = __expf(2.0f * x);
    return 1.0f - 2.0f / (e + 1.0f);
}

// ---------- async global->LDS 16B ----------
__device__ __forceinline__ void async_copy16(const void* g, void* l) {
    __builtin_amdgcn_global_load_lds(
        (const __attribute__((address_space(1))) unsigned int*)g,
        (__attribute__((address_space(3))) unsigned int*)l,
        16, 0, 0);
}

// ---------- fused prep (PROVEN function, verbatim; do_enc=0) ----------
__global__ void prep_all(const float* __restrict__ enc, const float* __restrict__ attn_w,
                         const float* __restrict__ attn_b, const float* __restrict__ hidden,
                         unsigned short* __restrict__ ebf, unsigned short* __restrict__ w2b,
                         float* __restrict__ dvec, float* __restrict__ logits, int do_enc) {
    int b = blockIdx.x;
    if (b < 32) {
        // zero the logits (gemm accumulates via atomicAdd)
        ((float4*)logits)[b * 256 + threadIdx.x] = (float4){0.f, 0.f, 0.f, 0.f};
        return;
    }
    b -= 32;
    if (do_enc) {
        if (b < 32768) {
            size_t idx4 = (size_t)b * 256 + threadIdx.x;       // float4 chunk id
            float4 f = ((const float4*)enc)[idx4];
            ushort4 u;
            u.x = f2bf(f.x); u.y = f2bf(f.y); u.z = f2bf(f.z); u.w = f2bf(f.w);
            ((ushort4*)ebf)[idx4] = u;
            return;
        }
        b -= 32768;
    }
    if (b < 1024) {
        // W2 = attn_w[:, 2048:3072] -> bf16 row-major (N=1024 x K=1024)
        int idx4 = b * 256 + threadIdx.x;
        int n = idx4 >> 8;
        int c = (idx4 & 255) * 4;
        float4 f = *(const float4*)(attn_w + (size_t)n * H3 + H2 + c);
        ushort4 u;
        u.x = f2bf(f.x); u.y = f2bf(f.y); u.z = f2bf(f.z); u.w = f2bf(f.w);
        *(ushort4*)(w2b + (size_t)n * H + c) = u;
        return;
    }
    // dvec[i] = attn_b[i] + sum_{k<2048} hidden[k]*attn_w[i][k]
    b -= 1024;
    int wv = threadIdx.x >> 6, lane = threadIdx.x & 63;
    int row = b * 4 + wv;
    const float* wrow = attn_w + (size_t)row * H3;
    float s = 0.f;
    #pragma unroll
    for (int j = 0; j < 32; ++j) {
        int k = lane + j * 64;
        s += wrow[k] * hidden[k];
    }
    #pragma unroll
    for (int m = 1; m <= 32; m <<= 1) s += __shfl_xor(s, m);
    if (lane == 0) dvec[row] = s + attn_b[row];
}

// ---------- shared epilogue: tanh + v_w-dot + shuffle-reduce + atomic ----------
__device__ __forceinline__ void epilogue(const f32x4 acc[4][4], const float* __restrict__ dvec,
                                         const float* __restrict__ vw, float* __restrict__ logits,
                                         int rowBlock, int colBlock, int waveM, int waveN,
                                         int quad, int l16) {
    float rowsum[4][4];
    #pragma unroll
    for (int mi = 0; mi < 4; ++mi)
        #pragma unroll
        for (int r = 0; r < 4; ++r) rowsum[mi][r] = 0.f;

    #pragma unroll
    for (int ni = 0; ni < 4; ++ni) {
        int colg = colBlock * 128 + waveN * 64 + ni * 16 + l16;
        float dv = dvec[colg];
        float vv = vw[colg];
        #pragma unroll
        for (int mi = 0; mi < 4; ++mi)
            #pragma unroll
            for (int r = 0; r < 4; ++r)
                rowsum[mi][r] += tanh_fast(acc[mi][ni][r] + dv) * vv;
    }

    #pragma unroll
    for (int mi = 0; mi < 4; ++mi)
        #pragma unroll
        for (int r = 0; r < 4; ++r) {
            float s = rowsum[mi][r];
            s += __shfl_xor(s, 1);
            s += __shfl_xor(s, 2);
            s += __shfl_xor(s, 4);
            s += __shfl_xor(s, 8);
            rowsum[mi][r] = s;
        }

    if (l16 == 0) {
        int rbase = rowBlock * 128 + waveM * 64 + quad * 4;
        #pragma unroll
        for (int mi = 0; mi < 4; ++mi)
            #pragma unroll
            for (int r = 0; r < 4; ++r)
                atomicAdd(&logits[rbase + mi * 16 + r], rowsum[mi][r]);
    }
}

// ---------- fused gemm v2: pure global_load_lds, fixed swizzles ----------
// Changes vs round-8 (which passed refcheck but was slow):
// 1. XCD-CHUNKED grid decode: XCD = blockIdx&7 owns rows 32x..32x+31,
//    col-fastest: rowBlock=(b&7)*32+(b>>6), colBlock=(b>>3)&7. The 8 blocks
//    sharing an A-panel are CONSECUTIVE slots on the SAME XCD -> panel stays
//    L2-hot (~8 live panels x 512 KB ~ 4 MB L2). Round-8 decode separated
//    sharers by 256 blocks -> L2 thrash -> FETCH 415 MB (3.3x A).
// 2. A LDS full 16-slot XOR swizzle: row r (256 B = 16 chunks of 16B), slot j
//    holds k-chunk j^(r&15). Read path: ar&15==l16, so a 16-lane group reads
//    16 DISTINCT slots (bijective in l16) -> zero bank conflicts. Round-8's
//    even-XOR spread only 8 offsets -> 8-way alias -> 8.4M conflict cycles.
// B path byte-identical to the proven round-0/6 kernel.
__global__ __launch_bounds__(256, 2) void attn_gemm_f32a(
        const float* __restrict__ enc, const unsigned short* __restrict__ w2b,
        const float* __restrict__ dvec, const float* __restrict__ vw,
        float* __restrict__ logits) {
    __shared__ float Af[128 * 64];               // 32 KB fp32 A tile
    __shared__ unsigned short Btile[128 * 64];   // 16 KB bf16 B tile

    const int tid = threadIdx.x;
    const int b = blockIdx.x;
    const int rowBlock = (b & 7) * 32 + (b >> 6);   // XCD-chunked (bijective)
    const int colBlock = (b >> 3) & 7;

    const int lane = tid & 63;
    const int wv = tid >> 6;
    const int waveM = wv >> 1, waveN = wv & 1;
    const int quad = lane >> 4, l16 = lane & 15;

    f32x4 acc[4][4];
    #pragma unroll
    for (int mi = 0; mi < 4; ++mi)
        #pragma unroll
        for (int ni = 0; ni < 4; ++ni)
            acc[mi][ni] = (f32x4){0.f, 0.f, 0.f, 0.f};

    const size_t aRow0 = (size_t)(rowBlock * 128) * H;   // fp32 elements
    const size_t bRow0 = (size_t)(colBlock * 128) * H;   // bf16 elements

    // A staging: 2048 chunks of 16B; 8 per thread. c = chunk id.
    // row = c>>4, slot = c&15, stored k-chunk = slot^(row&15)
    int srA[8], skA[8];
    #pragma unroll
    for (int p = 0; p < 8; ++p) {
        int c = p * 256 + tid;
        srA[p] = c >> 4;
        skA[p] = ((c & 15) ^ (srA[p] & 15)) * 4;   // fp32-element offset
    }
    // B staging (proven): row = c>>3, slot = c&7, k-chunk = slot^(row&7)
    int srB[4], skB[4];
    #pragma unroll
    for (int p = 0; p < 4; ++p) {
        int c = p * 256 + tid;
        srB[p] = c >> 3;
        skB[p] = ((c & 7) ^ (srB[p] & 7)) * 8;     // bf16-element offset
    }

    for (int kt = 0; kt < 16; ++kt) {
        const int k0 = kt * 64;

        // A: fp32 tile via pure global_load_lds (8 x 16B per thread)
        #pragma unroll
        for (int p = 0; p < 8; ++p) {
            int c = p * 256 + tid;
            async_copy16(enc + aRow0 + (size_t)srA[p] * H + k0 + skA[p],
                         (char*)Af + (size_t)c * 16);
        }
        // B: bf16 tile via pure global_load_lds (4 x 16B per thread)
        #pragma unroll
        for (int p = 0; p < 4; ++p) {
            int c = p * 256 + tid;
            async_copy16(w2b + bRow0 + (size_t)srB[p] * H + k0 + skB[p],
                         (char*)Btile + (size_t)c * 16);
        }

        __syncthreads();   // compiler drains vmcnt(0) before barrier

        #pragma unroll
        for (int kk = 0; kk < 2; ++kk) {
            const int bslot = ((kk * 4 + quad) ^ (l16 & 7)) * 16;  // B byte offset
            bf16x8 af[4], bfr[4];
            #pragma unroll
            for (int i = 0; i < 4; ++i) {
                int ar = waveM * 64 + i * 16 + l16;
                // fragment = k-chunks {cb, cb+1}; chunk cc at slot cc^l16
                int cb = kk * 8 + quad * 2;               // even
                const float* ap0 = Af + ar * 64 + ((cb)     ^ l16) * 4;
                const float* ap1 = Af + ar * 64 + ((cb + 1) ^ l16) * 4;
                float4 lo = *(const float4*)ap0;
                float4 hi = *(const float4*)ap1;
                uint4 u;
                u.x = cvt_pk(lo.x, lo.y);
                u.y = cvt_pk(lo.z, lo.w);
                u.z = cvt_pk(hi.x, hi.y);
                u.w = cvt_pk(hi.z, hi.w);
                __builtin_memcpy(&af[i], &u, 16);

                int br = waveN * 64 + i * 16 + l16;
                bfr[i] = *(const bf16x8*)((const char*)Btile + br * 128 + bslot);
            }
            #pragma unroll
            for (int mi = 0; mi < 4; ++mi)
                #pragma unroll
                for (int ni = 0; ni < 4; ++ni)
                    acc[mi][ni] = __builtin_amdgcn_mfma_f32_16x16x32_bf16(
                        af[mi], bfr[ni], acc[mi][ni], 0, 0, 0);
        }

        __syncthreads();   // tile consumed; next iter may overwrite
    }

    epilogue(acc, dvec, vw, logits, rowBlock, colBlock, waveM, waveN, quad, l16);
}

// ---------- softmax over 32768 logits, single workgroup, in-place ----------
__global__ __launch_bounds__(1024) void softmax_k(float* __restrict__ x) {
    __shared__ float red[16];
    const int tid = threadIdx.x;
    const int lane = tid & 63, wv = tid >> 6;

    float v[32];
    float m = -1e30f;
    #pragma unroll
    for (int i = 0; i < 32; ++i) {
        v[i] = x[tid + (i << 10)];
        m = fmaxf(m, v[i]);
    }
    #pragma unroll
    for (int o = 1; o < 64; o <<= 1) m = fmaxf(m, __shfl_xor(m, o));
    if (lane == 0) red[wv] = m;
    __syncthreads();
    #pragma unroll
    for (int i = 0; i < 16; ++i) m = fmaxf(m, red[i]);
    __syncthreads();

    float s = 0.f;
    #pragma unroll
    for (int i = 0; i < 32; ++i) {
        v[i] = expf(v[i] - m);
        s += v[i];
    }
    #pragma unroll
    for (int o = 1; o < 64; o <<= 1) s += __shfl_xor(s, o);
    if (lane == 0) red[wv] = s;
    __syncthreads();
    float tot = 0.f;
    #pragma unroll
    for (int i = 0; i < 16; ++i) tot += red[i];
    float inv = 1.0f / tot;

    #pragma unroll
    for (int i = 0; i < 32; ++i) x[tid + (i << 10)] = v[i] * inv;
}

extern "C" void kernel_launch(void* const* d_in, const int* in_sizes, int n_in,
                              void* d_out, int out_size, void* d_ws, size_t ws_size,
                              hipStream_t stream) {
    const float* hidden = (const float*)d_in[0];   // (1, 2048)
    const float* enc    = (const float*)d_in[1];   // (32768, 1024)
    const float* attn_w = (const float*)d_in[2];   // (1024, 3072)
    const float* attn_b = (const float*)d_in[3];   // (1024,)
    const float* v_w    = (const float*)d_in[4];   // (1, 1024)
    float* out = (float*)d_out;                    // (32768,) fp32

    const size_t W2_BYTES = (size_t)H * H * 2;     // 2 MB
    unsigned short* w2b = (unsigned short*)d_ws;
    float* dvec = (float*)((char*)d_ws + W2_BYTES);

    // prep (proven function, do_enc=0): zero logits + W2->bf16 + dvec
    prep_all<<<dim3(32 + 1024 + 256), dim3(256), 0, stream>>>(
        enc, attn_w, attn_b, hidden, nullptr, w2b, dvec, out, 0);
    attn_gemm_f32a<<<dim3(2048), dim3(256), 0, stream>>>(enc, w2b, dvec, v_w, out);
    softmax_k<<<dim3(1), dim3(1024), 0, stream>>>(out);
}

// Round 10
// 284.754 us; speedup vs baseline: 1.1833x; 1.1367x over previous
//
#include <hip/hip_runtime.h>
#include <hip/hip_bf16.h>

#define H  1024
#define S  32768
#define H2 2048
#define H3 3072

typedef __attribute__((ext_vector_type(8))) short bf16x8;   // 8 bf16 = 4 VGPRs
typedef __attribute__((ext_vector_type(4))) float f32x4;    // MFMA C/D frag

// ---------- fp32 -> bf16 (RNE) helpers ----------
__device__ __forceinline__ unsigned short f2bf(float f) {
    unsigned u = __float_as_uint(f);
    u += 0x7fffu + ((u >> 16) & 1u);
    return (unsigned short)(u >> 16);
}

__device__ __forceinline__ unsigned cvt_pk(float lo, float hi) {
    __hip_bfloat162 h = __float22bfloat162_rn(make_float2(lo, hi));
    unsigned u;
    __builtin_memcpy(&u, &h, 4);
    return u;
}

// fast tanh via v_exp_f32: tanh(x) = 1 - 2/(e^(2x)+1)
__device__ __forceinline__ float tanh_fast(float x) {
    float e = __expf(2.0f * x);
    return 1.0f - 2.0f / (e + 1.0f);
}

// ---------- async global->LDS 16B ----------
__device__ __forceinline__ void async_copy16(const void* g, void* l) {
    __builtin_amdgcn_global_load_lds(
        (const __attribute__((address_space(1))) unsigned int*)g,
        (__attribute__((address_space(3))) unsigned int*)l,
        16, 0, 0);
}

// ---------- fused prep (PROVEN function, verbatim; do_enc=0) ----------
__global__ void prep_all(const float* __restrict__ enc, const float* __restrict__ attn_w,
                         const float* __restrict__ attn_b, const float* __restrict__ hidden,
                         unsigned short* __restrict__ ebf, unsigned short* __restrict__ w2b,
                         float* __restrict__ dvec, float* __restrict__ logits, int do_enc) {
    int b = blockIdx.x;
    if (b < 32) {
        // zero the logits (gemm accumulates via atomicAdd)
        ((float4*)logits)[b * 256 + threadIdx.x] = (float4){0.f, 0.f, 0.f, 0.f};
        return;
    }
    b -= 32;
    if (do_enc) {
        if (b < 32768) {
            size_t idx4 = (size_t)b * 256 + threadIdx.x;       // float4 chunk id
            float4 f = ((const float4*)enc)[idx4];
            ushort4 u;
            u.x = f2bf(f.x); u.y = f2bf(f.y); u.z = f2bf(f.z); u.w = f2bf(f.w);
            ((ushort4*)ebf)[idx4] = u;
            return;
        }
        b -= 32768;
    }
    if (b < 1024) {
        // W2 = attn_w[:, 2048:3072] -> bf16 row-major (N=1024 x K=1024)
        int idx4 = b * 256 + threadIdx.x;
        int n = idx4 >> 8;
        int c = (idx4 & 255) * 4;
        float4 f = *(const float4*)(attn_w + (size_t)n * H3 + H2 + c);
        ushort4 u;
        u.x = f2bf(f.x); u.y = f2bf(f.y); u.z = f2bf(f.z); u.w = f2bf(f.w);
        *(ushort4*)(w2b + (size_t)n * H + c) = u;
        return;
    }
    // dvec[i] = attn_b[i] + sum_{k<2048} hidden[k]*attn_w[i][k]
    b -= 1024;
    int wv = threadIdx.x >> 6, lane = threadIdx.x & 63;
    int row = b * 4 + wv;
    const float* wrow = attn_w + (size_t)row * H3;
    float s = 0.f;
    #pragma unroll
    for (int j = 0; j < 32; ++j) {
        int k = lane + j * 64;
        s += wrow[k] * hidden[k];
    }
    #pragma unroll
    for (int m = 1; m <= 32; m <<= 1) s += __shfl_xor(s, m);
    if (lane == 0) dvec[row] = s + attn_b[row];
}

// ---------- fused gemm v3: BM=128 x BN=256 (halves A staging redundancy) ----------
// ROUND-9 POST-MORTEM: fixing fetch (415->90MB) and bank conflicts (8.4M->0)
// left dur unchanged at 173us -> the kernel is STAGING-BANDWIDTH-bound:
// dur ~ bytes staged into LDS per CU (~19 B/cyc/CU empirical across r0/r8/r9).
// Staged totals: A = 128MB * (1024/BN), B = 2MB * (32768/BM).
// r9 (128x128): 1024+512 = 1536 MB -> 173us. This kernel (128x256):
// 512+512 = 1024 MB (same as round-0's 88us config, but with NO 206MB
// pre-conversion pass). Predicted gemm ~105-120us.
//
// Structure kept maximally proven: pure global_load_lds both operands (no
// reg/DMA mixing - the crash trigger), single-buffered, one barrier pair/iter.
// A path byte-identical to round 9 (fp32, 16-slot XOR swizzle, 0 conflicts).
// B path = proven 8-slot XOR layout, extended to 256 rows.
// Grid 1024 blocks: XCD-chunked decode, 4 colBlocks consecutive per rowBlock
// on the same XCD (A-panel L2-hot): rowBlock=(b&7)*32+(b>>5), col=(b>>3)&3.
__global__ __launch_bounds__(256, 2) void attn_gemm_f32a(
        const float* __restrict__ enc, const unsigned short* __restrict__ w2b,
        const float* __restrict__ dvec, const float* __restrict__ vw,
        float* __restrict__ logits) {
    __shared__ float Af[128 * 64];               // 32 KB fp32 A tile
    __shared__ unsigned short Btile[256 * 64];   // 32 KB bf16 B tile (256 cols)

    const int tid = threadIdx.x;
    const int b = blockIdx.x;
    const int rowBlock = (b & 7) * 32 + (b >> 5);   // 0..255 (bijective)
    const int colBlock = (b >> 3) & 3;              // 0..3

    const int lane = tid & 63;
    const int wv = tid >> 6;
    const int waveM = wv >> 1, waveN = wv & 1;      // wave tile: 64 rows x 128 cols
    const int quad = lane >> 4, l16 = lane & 15;

    f32x4 acc[4][8];
    #pragma unroll
    for (int mi = 0; mi < 4; ++mi)
        #pragma unroll
        for (int ni = 0; ni < 8; ++ni)
            acc[mi][ni] = (f32x4){0.f, 0.f, 0.f, 0.f};

    const size_t aRow0 = (size_t)(rowBlock * 128) * H;   // fp32 elements
    const size_t bRow0 = (size_t)(colBlock * 256) * H;   // bf16 elements

    // A staging: 2048 chunks of 16B; 8 per thread. row = c>>4, slot = c&15,
    // stored k-chunk = slot^(row&15)  (round-9 verified: 0 conflicts)
    int srA[8], skA[8];
    #pragma unroll
    for (int p = 0; p < 8; ++p) {
        int c = p * 256 + tid;
        srA[p] = c >> 4;
        skA[p] = ((c & 15) ^ (srA[p] & 15)) * 4;   // fp32-element offset
    }
    // B staging: 2048 chunks (256 rows x 8); 8 per thread. row = c>>3,
    // slot = c&7, stored k-chunk = slot^(row&7)  (proven layout)
    int srB[8], skB[8];
    #pragma unroll
    for (int p = 0; p < 8; ++p) {
        int c = p * 256 + tid;
        srB[p] = c >> 3;
        skB[p] = ((c & 7) ^ (srB[p] & 7)) * 8;     // bf16-element offset
    }

    for (int kt = 0; kt < 16; ++kt) {
        const int k0 = kt * 64;

        // A: fp32 tile via pure global_load_lds (8 x 16B per thread)
        #pragma unroll
        for (int p = 0; p < 8; ++p) {
            int c = p * 256 + tid;
            async_copy16(enc + aRow0 + (size_t)srA[p] * H + k0 + skA[p],
                         (char*)Af + (size_t)c * 16);
        }
        // B: bf16 tile via pure global_load_lds (8 x 16B per thread)
        #pragma unroll
        for (int p = 0; p < 8; ++p) {
            int c = p * 256 + tid;
            async_copy16(w2b + bRow0 + (size_t)srB[p] * H + k0 + skB[p],
                         (char*)Btile + (size_t)c * 16);
        }

        __syncthreads();   // compiler drains vmcnt(0) before barrier

        #pragma unroll
        for (int kk = 0; kk < 2; ++kk) {
            const int bslot = ((kk * 4 + quad) ^ (l16 & 7)) * 16;  // B byte offset
            bf16x8 af[4], bfr[8];
            #pragma unroll
            for (int i = 0; i < 4; ++i) {
                int ar = waveM * 64 + i * 16 + l16;
                // fragment = k-chunks {cb, cb+1}; chunk cc stored at slot cc^l16
                int cb = kk * 8 + quad * 2;               // even
                const float* ap0 = Af + ar * 64 + ((cb)     ^ l16) * 4;
                const float* ap1 = Af + ar * 64 + ((cb + 1) ^ l16) * 4;
                float4 lo = *(const float4*)ap0;
                float4 hi = *(const float4*)ap1;
                uint4 u;
                u.x = cvt_pk(lo.x, lo.y);
                u.y = cvt_pk(lo.z, lo.w);
                u.z = cvt_pk(hi.x, hi.y);
                u.w = cvt_pk(hi.z, hi.w);
                __builtin_memcpy(&af[i], &u, 16);
            }
            #pragma unroll
            for (int j = 0; j < 8; ++j) {
                int br = waveN * 128 + j * 16 + l16;
                bfr[j] = *(const bf16x8*)((const char*)Btile + br * 128 + bslot);
            }
            #pragma unroll
            for (int mi = 0; mi < 4; ++mi)
                #pragma unroll
                for (int ni = 0; ni < 8; ++ni)
                    acc[mi][ni] = __builtin_amdgcn_mfma_f32_16x16x32_bf16(
                        af[mi], bfr[ni], acc[mi][ni], 0, 0, 0);
        }

        __syncthreads();   // tile consumed; next iter may overwrite
    }

    // ---------- epilogue: tanh + v_w-dot + shuffle-reduce + atomic ----------
    float rowsum[4][4];
    #pragma unroll
    for (int mi = 0; mi < 4; ++mi)
        #pragma unroll
        for (int r = 0; r < 4; ++r) rowsum[mi][r] = 0.f;

    #pragma unroll
    for (int ni = 0; ni < 8; ++ni) {
        int colg = colBlock * 256 + waveN * 128 + ni * 16 + l16;
        float dv = dvec[colg];
        float vv = vw[colg];
        #pragma unroll
        for (int mi = 0; mi < 4; ++mi)
            #pragma unroll
            for (int r = 0; r < 4; ++r)
                rowsum[mi][r] += tanh_fast(acc[mi][ni][r] + dv) * vv;
    }

    #pragma unroll
    for (int mi = 0; mi < 4; ++mi)
        #pragma unroll
        for (int r = 0; r < 4; ++r) {
            float s = rowsum[mi][r];
            s += __shfl_xor(s, 1);
            s += __shfl_xor(s, 2);
            s += __shfl_xor(s, 4);
            s += __shfl_xor(s, 8);
            rowsum[mi][r] = s;
        }

    if (l16 == 0) {
        int rbase = rowBlock * 128 + waveM * 64 + quad * 4;
        #pragma unroll
        for (int mi = 0; mi < 4; ++mi)
            #pragma unroll
            for (int r = 0; r < 4; ++r)
                atomicAdd(&logits[rbase + mi * 16 + r], rowsum[mi][r]);
    }
}

// ---------- softmax over 32768 logits, single workgroup, in-place ----------
__global__ __launch_bounds__(1024) void softmax_k(float* __restrict__ x) {
    __shared__ float red[16];
    const int tid = threadIdx.x;
    const int lane = tid & 63, wv = tid >> 6;

    float v[32];
    float m = -1e30f;
    #pragma unroll
    for (int i = 0; i < 32; ++i) {
        v[i] = x[tid + (i << 10)];
        m = fmaxf(m, v[i]);
    }
    #pragma unroll
    for (int o = 1; o < 64; o <<= 1) m = fmaxf(m, __shfl_xor(m, o));
    if (lane == 0) red[wv] = m;
    __syncthreads();
    #pragma unroll
    for (int i = 0; i < 16; ++i) m = fmaxf(m, red[i]);
    __syncthreads();

    float s = 0.f;
    #pragma unroll
    for (int i = 0; i < 32; ++i) {
        v[i] = expf(v[i] - m);
        s += v[i];
    }
    #pragma unroll
    for (int o = 1; o < 64; o <<= 1) s += __shfl_xor(s, o);
    if (lane == 0) red[wv] = s;
    __syncthreads();
    float tot = 0.f;
    #pragma unroll
    for (int i = 0; i < 16; ++i) tot += red[i];
    float inv = 1.0f / tot;

    #pragma unroll
    for (int i = 0; i < 32; ++i) x[tid + (i << 10)] = v[i] * inv;
}

extern "C" void kernel_launch(void* const* d_in, const int* in_sizes, int n_in,
                              void* d_out, int out_size, void* d_ws, size_t ws_size,
                              hipStream_t stream) {
    const float* hidden = (const float*)d_in[0];   // (1, 2048)
    const float* enc    = (const float*)d_in[1];   // (32768, 1024)
    const float* attn_w = (const float*)d_in[2];   // (1024, 3072)
    const float* attn_b = (const float*)d_in[3];   // (1024,)
    const float* v_w    = (const float*)d_in[4];   // (1, 1024)
    float* out = (float*)d_out;                    // (32768,) fp32

    const size_t W2_BYTES = (size_t)H * H * 2;     // 2 MB
    unsigned short* w2b = (unsigned short*)d_ws;
    float* dvec = (float*)((char*)d_ws + W2_BYTES);

    // prep (proven function, do_enc=0): zero logits + W2->bf16 + dvec
    prep_all<<<dim3(32 + 1024 + 256), dim3(256), 0, stream>>>(
        enc, attn_w, attn_b, hidden, nullptr, w2b, dvec, out, 0);
    attn_gemm_f32a<<<dim3(1024), dim3(256), 0, stream>>>(enc, w2b, dvec, v_w, out);
    softmax_k<<<dim3(1), dim3(1024), 0, stream>>>(out);
}